// Round 11
// baseline (619.097 us; speedup 1.0000x reference)
//
#include <hip/hip_runtime.h>
#include <math.h>

typedef _Float16 f16;
typedef __attribute__((ext_vector_type(8))) _Float16 f16x8;
typedef __attribute__((ext_vector_type(4))) _Float16 f16x4;
typedef __attribute__((ext_vector_type(4))) float f32x4;

#define BB   8
#define NN   2304
#define CIN  512
#define HID  256
#define QKV3 768
#define MM   (BB * NN)
#define SCALE 0.125f

#define MFMA16(a, b, c) __builtin_amdgcn_mfma_f32_16x16x32_f16(a, b, c, 0, 0, 0)

// ---------------------------------------------------------------------------
// Transpose + f32->f16: Wt[n][k] = (f16)W[k][n]
// ---------------------------------------------------------------------------
__global__ __launch_bounds__(256) void transpose_f32_to_f16(
    const float* __restrict__ W, f16* __restrict__ Wt, int K, int N)
{
    __shared__ float tile[32][33];
    const int tx = threadIdx.x & 31, ty = threadIdx.x >> 5;
    const int n0 = blockIdx.x * 32, k0 = blockIdx.y * 32;
#pragma unroll
    for (int i = 0; i < 4; ++i)
        tile[ty + i * 8][tx] = W[(long)(k0 + ty + i * 8) * N + n0 + tx];
    __syncthreads();
#pragma unroll
    for (int i = 0; i < 4; ++i)
        Wt[(long)(n0 + ty + i * 8) * K + k0 + tx] = (f16)tile[tx][ty + i * 8];
}

// ---------------------------------------------------------------------------
// MFMA GEMM: C = A @ Bt^T + bias.  Bt is [Ndim][Kdim] f16 (pre-transposed W).
// Tile 128x128, BK=64, 256 threads, 4 waves (2x2), 64x64 per wave.
// VAR 0: A = f32, C = f16 (qkv; scale cols<256 by 0.125 after bias)
// VAR 1: A = f16, C = f32
// ---------------------------------------------------------------------------
template <int VAR>
__global__ __launch_bounds__(256) void gemm_mfma(
    const void* __restrict__ Ap, const f16* __restrict__ Bt,
    const float* __restrict__ bias, void* __restrict__ Cp,
    int Kdim, int Ndim, int NB)
{
    __shared__ char lds[32768];
    char* As = lds;           // [128][128B] f16, byte = row*128 + (col2 ^ ((row&7)<<4))
    char* Bs = lds + 16384;   // 128B rows: (row&7)<<4 <= 112 < 128, bijective OK

    const int t = threadIdx.x;
    const int lane = t & 63;
    const int w = t >> 6;
    const int chunk = gridDim.x >> 3;                      // gridDim.x % 8 == 0
    const int bsw = (blockIdx.x & 7) * chunk + (blockIdx.x >> 3);
    const int m0 = (bsw / NB) * 128;
    const int n0 = (bsw % NB) * 128;
    const int wm = (w >> 1) * 64;
    const int wn = (w & 1) * 64;
    const int NK = Kdim >> 6;

    f32x4 acc[4][4];
#pragma unroll
    for (int i = 0; i < 4; ++i)
#pragma unroll
        for (int j = 0; j < 4; ++j) acc[i][j] = (f32x4){0.f, 0.f, 0.f, 0.f};

    float4 a32[8];
    int4   a16[4];
    int4   breg[4];

    auto loadA = [&](int kt) {
        if (VAR == 0) {
            const float* A = (const float*)Ap;
#pragma unroll
            for (int i = 0; i < 8; ++i) {
                const int cid = t + i * 256, row = cid >> 4, cir = cid & 15;
                a32[i] = *(const float4*)&A[(long)(m0 + row) * Kdim + kt * 64 + cir * 4];
            }
        } else {
            const f16* A = (const f16*)Ap;
#pragma unroll
            for (int i = 0; i < 4; ++i) {
                const int cid = t + i * 256, row = cid >> 3, cir = cid & 7;
                a16[i] = *(const int4*)&A[(long)(m0 + row) * Kdim + kt * 64 + cir * 8];
            }
        }
#pragma unroll
        for (int i = 0; i < 4; ++i) {
            const int cid = t + i * 256, row = cid >> 3, cir = cid & 7;
            breg[i] = *(const int4*)&Bt[(long)(n0 + row) * Kdim + kt * 64 + cir * 8];
        }
    };
    auto writeLDS = [&]() {
        if (VAR == 0) {
#pragma unroll
            for (int i = 0; i < 8; ++i) {
                const int cid = t + i * 256, row = cid >> 4, cir = cid & 15;
                f16x4 v = {(f16)a32[i].x, (f16)a32[i].y, (f16)a32[i].z, (f16)a32[i].w};
                *(f16x4*)(As + row * 128 + ((cir * 8) ^ ((row & 7) << 4))) = v;
            }
        } else {
#pragma unroll
            for (int i = 0; i < 4; ++i) {
                const int cid = t + i * 256, row = cid >> 3, cir = cid & 7;
                *(int4*)(As + row * 128 + ((cir * 16) ^ ((row & 7) << 4))) = a16[i];
            }
        }
#pragma unroll
        for (int i = 0; i < 4; ++i) {
            const int cid = t + i * 256, row = cid >> 3, cir = cid & 7;
            *(int4*)(Bs + row * 128 + ((cir * 16) ^ ((row & 7) << 4))) = breg[i];
        }
    };

    loadA(0);
    writeLDS();
    __syncthreads();

    for (int kt = 0; kt < NK; ++kt) {
        if (kt + 1 < NK) loadA(kt + 1);
#pragma unroll
        for (int ks = 0; ks < 2; ++ks) {
            f16x8 af[4], bf[4];
            const int kb = (ks * 32 + ((lane >> 4) * 8)) * 2;
#pragma unroll
            for (int mb = 0; mb < 4; ++mb) {
                const int row = wm + mb * 16 + (lane & 15);
                af[mb] = *(const f16x8*)(As + row * 128 + (kb ^ ((row & 7) << 4)));
            }
#pragma unroll
            for (int nb = 0; nb < 4; ++nb) {
                const int row = wn + nb * 16 + (lane & 15);
                bf[nb] = *(const f16x8*)(Bs + row * 128 + (kb ^ ((row & 7) << 4)));
            }
#pragma unroll
            for (int mb = 0; mb < 4; ++mb)
#pragma unroll
                for (int nb = 0; nb < 4; ++nb)
                    acc[mb][nb] = MFMA16(af[mb], bf[nb], acc[mb][nb]);
        }
        __syncthreads();
        if (kt + 1 < NK) { writeLDS(); __syncthreads(); }
    }

#pragma unroll
    for (int nb = 0; nb < 4; ++nb) {
        const int col = n0 + wn + nb * 16 + (lane & 15);
        const float bv = bias[col];
        const float sc = (VAR == 0 && col < HID) ? SCALE : 1.0f;
#pragma unroll
        for (int mb = 0; mb < 4; ++mb)
#pragma unroll
            for (int j = 0; j < 4; ++j) {
                const int row = m0 + wm + mb * 16 + (lane >> 4) * 4 + j;
                const float v = (acc[mb][nb][j] + bv) * sc;
                if (VAR == 0) ((f16*)Cp)[(long)row * Ndim + col] = (f16)v;
                else          ((float*)Cp)[(long)row * Ndim + col] = v;
            }
    }
}

// ---------------------------------------------------------------------------
// Flash attention, f16 MFMA, within-block KV-split.
// qkv rows: [q*0.125 (256) | k (256) | v (256)] f16.
// Block: 256 thr (4 waves). wave w: rg=w&1 (q-row group of 16), kh=w>>1
// (kv half). QM=32 q-rows/block, KT=32 kv/tile.
// SWIZZLE RULE (r7): XOR stripe must stay inside the row (bijective).
// LAUNCH BOUNDS (r10 lesson): (256,2) capped VGPR at 128 < ~160 live state
// -> scratch spill (WRITE_SIZE 190 MB vs 9 MB output, vmcnt drains poisoned).
// LDS 70KB already limits to 2 blocks/CU; plain (256) keeps that without
// the spill (VGPR <= 256 still allows 8 waves/CU per m69).
// ---------------------------------------------------------------------------
#define QM 32
#define KT 32
#define KVHALF 1152
#define NT (KVHALF / KT)   // 36

__global__ __launch_bounds__(256) void attn_mfma(
    const f16* __restrict__ qkv, f16* __restrict__ attno)
{
    __shared__ char lds[69888];
    // [0, 32K): Ks, half kh at kh*16384: [32 rows][512B], swz ^((row&15)<<4)
    // [32K, 64K): Vt, half kh at 32768+kh*16384: [256 d][64B], swz ^((d&3)<<4)
    // [64K, 68K): P, wave w at 65536+w*1024: [16 rows][64B], swz ^((row&3)<<4)
    // epilogue reuse: [0,32K) o-f32 of kh=1 waves ([rg] 16KB: [16 rows][256 d])
    //                [69632+rg*128): m,l pairs (16 rows x 2 f32)

    const int t    = threadIdx.x;
    const int lane = t & 63;
    const int w    = t >> 6;
    const int rg   = w & 1;        // q-row group
    const int kh   = w >> 1;       // kv half
    const int tt   = t & 127;      // thread index within kv-half (2 waves)
    const int b    = blockIdx.x & 7;
    const int q0   = (blockIdx.x >> 3) * QM;
    const long base = (long)b * NN;
    const int kv0  = kh * KVHALF;

    char* KsH = lds + kh * 16384;
    char* VtH = lds + 32768 + kh * 16384;
    char* PwW = lds + 65536 + w * 1024;

    // ---- Q fragments in registers (wave's 16 rows, full D=256) ----
    const int qrow = q0 + rg * 16 + (lane & 15);
    f16x8 qf[8];
    {
        const f16* qsrc = qkv + (base + qrow) * QKV3 + ((lane >> 4) * 8);
#pragma unroll
        for (int ks = 0; ks < 8; ++ks)
            qf[ks] = *(const f16x8*)(qsrc + ks * 32);
    }

    f32x4 o[16];
#pragma unroll
    for (int i = 0; i < 16; ++i) o[i] = (f32x4){0.f, 0.f, 0.f, 0.f};
    float m[4], lsum[4];
#pragma unroll
    for (int j = 0; j < 4; ++j) { m[j] = -1e30f; lsum[j] = 0.f; }

    // staging maps (128 threads per half)
    const int vquad = tt & 7;        // 8 quads x 4 kv rows = 32 rows
    const int vdg   = (tt >> 3) * 16; // 16 d-groups x 16 d = 256

    int4  kreg[8];
    f16x8 vreg[8];
    auto loadTile = [&](int tile) {
        const long kbase = base + kv0 + tile * KT;
#pragma unroll
        for (int i = 0; i < 8; ++i) {
            const int cid = tt + i * 128, row = cid >> 5, cir = cid & 31;
            kreg[i] = *(const int4*)(qkv + (kbase + row) * QKV3 + 256 + cir * 8);
        }
#pragma unroll
        for (int r = 0; r < 4; ++r) {
            const f16* vs = qkv + (kbase + vquad * 4 + r) * QKV3 + 512 + vdg;
            vreg[r * 2]     = *(const f16x8*)(vs);
            vreg[r * 2 + 1] = *(const f16x8*)(vs + 8);
        }
    };
    auto writeTile = [&]() {
#pragma unroll
        for (int i = 0; i < 8; ++i) {
            const int cid = tt + i * 128, row = cid >> 5, cir = cid & 31;
            *(int4*)(KsH + row * 512 + ((cir * 16) ^ ((row & 15) << 4))) = kreg[i];
        }
#pragma unroll
        for (int i = 0; i < 16; ++i) {
            const int d = vdg + i;
            f16x4 wv;
#pragma unroll
            for (int r = 0; r < 4; ++r)
                wv[r] = (i < 8) ? vreg[r * 2][i] : vreg[r * 2 + 1][i - 8];
            *(f16x4*)(VtH + d * 64 + ((vquad * 8) ^ ((d & 3) << 4))) = wv;
        }
    };

    loadTile(0);

    for (int tile = 0; tile < NT; ++tile) {
        __syncthreads();            // previous tile's LDS reads complete
        writeTile();
        __syncthreads();            // staging visible
        if (tile + 1 < NT) loadTile(tile + 1);   // prefetch (hides under compute)

        // ---- S = Q @ K^T : 16 q x 32 kv ----
        f32x4 s[2];
        s[0] = (f32x4){0.f, 0.f, 0.f, 0.f};
        s[1] = (f32x4){0.f, 0.f, 0.f, 0.f};
        __builtin_amdgcn_s_setprio(1);
#pragma unroll
        for (int ks = 0; ks < 8; ++ks) {
            const int kb = (ks * 32 + (lane >> 4) * 8) * 2;
#pragma unroll
            for (int nb = 0; nb < 2; ++nb) {
                const int row = nb * 16 + (lane & 15);
                f16x8 kf = *(const f16x8*)(KsH + row * 512 + (kb ^ ((row & 15) << 4)));
                s[nb] = MFMA16(qf[ks], kf, s[nb]);
            }
        }
        __builtin_amdgcn_s_setprio(0);

        // ---- online softmax (row r = (lane>>4)*4 + j lives in 16-lane group) ----
        float f[4];
#pragma unroll
        for (int j = 0; j < 4; ++j) {
            float rmax = fmaxf(s[0][j], s[1][j]);
            rmax = fmaxf(rmax, __shfl_xor(rmax, 1));
            rmax = fmaxf(rmax, __shfl_xor(rmax, 2));
            rmax = fmaxf(rmax, __shfl_xor(rmax, 4));
            rmax = fmaxf(rmax, __shfl_xor(rmax, 8));
            const float mnew = fmaxf(m[j], rmax);
            f[j] = __expf(m[j] - mnew);
            const float p0 = __expf(s[0][j] - mnew);
            const float p1 = __expf(s[1][j] - mnew);
            float ps = p0 + p1;
            ps += __shfl_xor(ps, 1);
            ps += __shfl_xor(ps, 2);
            ps += __shfl_xor(ps, 4);
            ps += __shfl_xor(ps, 8);
            lsum[j] = lsum[j] * f[j] + ps;
            m[j] = mnew;
            const int prow = (lane >> 4) * 4 + j;
            char* pr = PwW + prow * 64;
            const int cb = (lane & 15) * 2;
            const int sw = (prow & 3) << 4;
            *(f16*)(pr + ((cb +  0) ^ sw)) = (f16)p0;
            *(f16*)(pr + ((cb + 32) ^ sw)) = (f16)p1;
        }
#pragma unroll
        for (int nb2 = 0; nb2 < 16; ++nb2)
#pragma unroll
            for (int j = 0; j < 4; ++j) o[nb2][j] *= f[j];

        asm volatile("s_waitcnt lgkmcnt(0)" ::: "memory");
        __builtin_amdgcn_sched_barrier(0);

        // ---- O += P @ V (single k-step: KT=32) ----
        {
            const int prow = lane & 15;
            const int kb = (lane >> 4) * 16;
            f16x8 pa = *(const f16x8*)(PwW + prow * 64 + (kb ^ ((prow & 3) << 4)));
            __builtin_amdgcn_s_setprio(1);
#pragma unroll
            for (int nb2 = 0; nb2 < 16; ++nb2) {
                const int d = nb2 * 16 + (lane & 15);
                f16x8 vb = *(const f16x8*)(VtH + d * 64 + (kb ^ ((d & 3) << 4)));
                o[nb2] = MFMA16(pa, vb, o[nb2]);
            }
            __builtin_amdgcn_s_setprio(0);
        }
    }

    // ---- merge kv-halves through LDS ----
    __syncthreads();
    if (kh == 1) {
        float* oL = (float*)(lds + rg * 16384);
#pragma unroll
        for (int nb2 = 0; nb2 < 16; ++nb2)
#pragma unroll
            for (int j = 0; j < 4; ++j)
                oL[((lane >> 4) * 4 + j) * 256 + nb2 * 16 + (lane & 15)] = o[nb2][j];
        if ((lane & 15) == 0) {
            float* ml = (float*)(lds + 69632 + rg * 128);
#pragma unroll
            for (int j = 0; j < 4; ++j) {
                const int row = (lane >> 4) * 4 + j;
                ml[row * 2]     = m[j];
                ml[row * 2 + 1] = lsum[j];
            }
        }
    }
    __syncthreads();
    if (kh == 0) {
        const float* oL = (const float*)(lds + rg * 16384);
        const float* ml = (const float*)(lds + 69632 + rg * 128);
#pragma unroll
        for (int j = 0; j < 4; ++j) {
            const int row = (lane >> 4) * 4 + j;
            const float m1 = ml[row * 2];
            const float l1 = ml[row * 2 + 1];
            const float M  = fmaxf(m[j], m1);
            const float e0 = __expf(m[j] - M);
            const float e1 = __expf(m1 - M);
            const float inv = 1.f / (lsum[j] * e0 + l1 * e1);
#pragma unroll
            for (int nb2 = 0; nb2 < 16; ++nb2) {
                const int col = nb2 * 16 + (lane & 15);
                const float v = (o[nb2][j] * e0 + oL[row * 256 + col] * e1) * inv;
                attno[(base + q0 + rg * 16 + row) * HID + col] = (f16)v;
            }
        }
    }
}

// ---------------------------------------------------------------------------
extern "C" void kernel_launch(void* const* d_in, const int* in_sizes, int n_in,
                              void* d_out, int out_size, void* d_ws, size_t ws_size,
                              hipStream_t stream)
{
    (void)in_sizes; (void)n_in; (void)out_size; (void)ws_size;
    const float* x  = (const float*)d_in[0];
    const float* W1 = (const float*)d_in[1];
    const float* b1 = (const float*)d_in[2];
    const float* W2 = (const float*)d_in[3];
    const float* b2 = (const float*)d_in[4];
    float* out = (float*)d_out;

    char* ws = (char*)d_ws;
    f16* W1t   = (f16*)ws;                               // 768*512  f16 = 768 KB
    f16* W2t   = (f16*)(ws + 786432);                    // 256*256  f16 = 128 KB
    f16* qkv   = (f16*)(ws + 786432 + 131072);           // 18432*768 f16 = 27 MB
    f16* attno = (f16*)(ws + 786432 + 131072 + 28311552);// 18432*256 f16 = 9 MB

    transpose_f32_to_f16<<<dim3(QKV3 / 32, CIN / 32), 256, 0, stream>>>(W1, W1t, CIN, QKV3);
    transpose_f32_to_f16<<<dim3(HID / 32, HID / 32), 256, 0, stream>>>(W2, W2t, HID, HID);
    // qkv = x @ W1 + b1 (f16 out, q pre-scaled)
    gemm_mfma<0><<<864, 256, 0, stream>>>(x, W1t, b1, qkv, CIN, QKV3, 6);
    // flash attention (within-block kv-split)
    attn_mfma<<<576, 256, 0, stream>>>(qkv, attno);
    // out = attno @ W2 + b2 (f32 out)
    gemm_mfma<1><<<288, 256, 0, stream>>>(attno, W2t, b2, out, HID, HID, 2);
}